// Round 3
// baseline (889.775 us; speedup 1.0000x reference)
//
#include <hip/hip_runtime.h>

#define SEQ   120
#define WARM  96
#define FLEN  24
#define HDIM  256

typedef __attribute__((ext_vector_type(8))) short bf16x8;
typedef __attribute__((ext_vector_type(4))) float floatx4;
typedef unsigned int uint;
typedef unsigned long long ull;

// ws layout (bytes):
//   WHI  [0, 512K)        bf16 frag-linear W-hi
//   WLO  [512K, 1M)       bf16 frag-linear W-lo
//   BB   [1M, +4K)        f32 b_ih+b_hh
//   WI   [1M+4K, +4K)     f32 W_ih col
//   BAR  [1M+8K, +8K)     uint bar[32], stride 64 uints (256 B)
//                         +0: step barrier, +16: init barrier, +32..39: xcc ids
//   H    [1M+16K, +4M)    bf16 h, UNPACKED [hi p0 | hi p1 | lo p0 | lo p1],
//                         each 1MB = [2048 rows][256 k] shorts, row-major
//   XT   [5M+16K, +960K)  f32 x transposed [t][row]
#define WHI_OFF 0
#define WLO_OFF (512 * 1024)
#define BB_OFF  (1024 * 1024)
#define WI_OFF  (1024 * 1024 + 4096)
#define BAR_OFF (1024 * 1024 + 8192)
#define HG_OFF  (1024 * 1024 + 16384)
#define HPAR    524288              // shorts per parity plane (1 MB)
#define HLO_S   1048576             // short offset of lo planes (+2 MB)
#define XT_OFF  (HG_OFF + 4 * 1024 * 1024)

#define LDS_BYTES 65792             // wlo 64K | y 256B

__device__ __forceinline__ short f2bf(float v) {
    unsigned u = __float_as_uint(v);
    u += 0x7FFF + ((u >> 16) & 1);              // RNE
    return (short)(u >> 16);
}
__device__ __forceinline__ float bf2f(short s) {
    return __uint_as_float(((unsigned)(unsigned short)s) << 16);
}
__device__ __forceinline__ float fast_sig(float x) {
    return 1.0f / (1.0f + __expf(-x));
}
__device__ __forceinline__ float fast_tanh(float x) {
    return 1.0f - 2.0f / (__expf(2.0f * x) + 1.0f);
}

__device__ __forceinline__ uint load_llc32u(const uint* p) {
    return __hip_atomic_load(p, __ATOMIC_RELAXED, __HIP_MEMORY_SCOPE_AGENT);
}
__device__ __forceinline__ void store_llc32(uint* p, uint v) {
    __hip_atomic_store(p, v, __ATOMIC_RELAXED, __HIP_MEMORY_SCOPE_AGENT);
}

// XCC (XCD) id of the CU executing this wave [measured: learn_hip m09]
__device__ __forceinline__ uint get_xcc_id() {
    uint x;
    asm volatile("s_getreg_b32 %0, hwreg(HW_REG_XCC_ID)" : "=s"(x));
    return x;
}

__global__ __launch_bounds__(256) void lstm_prep(
    const float* __restrict__ W_ih, const float* __restrict__ W_hh,
    const float* __restrict__ b_ih, const float* __restrict__ b_hh,
    const float* __restrict__ h0, const float* __restrict__ x,
    unsigned char* __restrict__ ws)
{
    int tid = blockIdx.x * 256 + threadIdx.x;       // grid 2048*256 = 524288
    if (tid < 262144) {
        int col = tid >> 8, k = tid & 255;          // col = gate*256+unit
        float v  = W_hh[tid];
        short hi = f2bf(v);
        short lo = f2bf(v - bf2f(hi));
        int g = col >> 8, rem = col & 255;
        int s = rem >> 5, uo = rem & 31, uc = uo >> 4, n = uo & 15;
        int kt = k >> 5, kq = (k >> 3) & 3, j = k & 7;
        size_t unit = ((((size_t)(s * 2 + uc) * 4 + g) * 8 + kt) * 64 + kq * 16 + n);
        ((short*)(ws + WHI_OFF))[unit * 8 + j] = hi;
        ((short*)(ws + WLO_OFF))[unit * 8 + j] = lo;
    }
    if (tid < 524288) {                              // h0 -> parity 0, [row][k]
        int row = tid >> 8, k = tid & 255;
        float v  = h0[tid];
        short hi = f2bf(v);
        short lo = f2bf(v - bf2f(hi));
        ((short*)(ws + HG_OFF))[(size_t)row * 256 + k]         = hi;
        ((short*)(ws + HG_OFF))[HLO_S + (size_t)row * 256 + k] = lo;
    }
    if (tid < 2048 * SEQ) {                          // x transpose -> [t][row]
        int row = tid / SEQ, tt = tid % SEQ;
        ((float*)(ws + XT_OFF))[tt * 2048 + row] = x[tid];
    }
    if (tid < 1024) {
        ((float*)(ws + BB_OFF))[tid] = b_ih[tid] + b_hh[tid];
        ((float*)(ws + WI_OFF))[tid] = W_ih[tid];
    }
    if (tid < 32) {
        ((uint*)(ws + BAR_OFF))[tid * 64]      = 0;   // step barrier
        ((uint*)(ws + BAR_OFF))[tid * 64 + 16] = 0;   // init barrier
    }
}

// ---- load 4 kt-chunks of A-fragments (hi+lo) directly from L2/LLC ----
// Lane l of wave (rt): row = rt*16 + (l&15), k = kt*32 + (l>>4)*8 .. +7.
// phi/plo are per-lane base pointers (include row*256 + kgrp*8).
template<bool LOC>
__device__ __forceinline__ void frag_load(bf16x8* fh, bf16x8* fl,
                                          const short* phi, const short* plo,
                                          int kt0)
{
    #pragma unroll
    for (int q = 0; q < 4; ++q) {
        const short* ph = phi + (kt0 + q) * 32;
        const short* pl = plo + (kt0 + q) * 32;
        if constexpr (LOC) {     // sc0: bypass stale L1, served by shared L2
            asm volatile("global_load_dwordx4 %0, %1, off sc0"
                         : "=v"(fh[q]) : "v"(ph));
            asm volatile("global_load_dwordx4 %0, %1, off sc0"
                         : "=v"(fl[q]) : "v"(pl));
        } else {                 // sc0 sc1: device-coherent (LLC) load
            asm volatile("global_load_dwordx4 %0, %1, off sc0 sc1"
                         : "=v"(fh[q]) : "v"(ph));
            asm volatile("global_load_dwordx4 %0, %1, off sc0 sc1"
                         : "=v"(fl[q]) : "v"(pl));
        }
    }
    asm volatile("s_waitcnt vmcnt(0)" ::: "memory");
    __builtin_amdgcn_sched_barrier(0);      // rule #18: pin consumers after wait
}

// y partial: p += fcw[k] * (h_hi + h_lo) over this lane's 4 kt-chunks
__device__ __forceinline__ float yacc(float p, const bf16x8* fh, const bf16x8* fl,
                                      const float* __restrict__ fcw,
                                      int kgrp, int kt0)
{
    #pragma unroll
    for (int q = 0; q < 4; ++q) {
        const float* w = fcw + (kt0 + q) * 32 + kgrp * 8;
        const float4 w0 = *(const float4*)(w);
        const float4 w1 = *(const float4*)(w + 4);
        p += w0.x * (bf2f(fh[q][0]) + bf2f(fl[q][0]));
        p += w0.y * (bf2f(fh[q][1]) + bf2f(fl[q][1]));
        p += w0.z * (bf2f(fh[q][2]) + bf2f(fl[q][2]));
        p += w0.w * (bf2f(fh[q][3]) + bf2f(fl[q][3]));
        p += w1.x * (bf2f(fh[q][4]) + bf2f(fl[q][4]));
        p += w1.y * (bf2f(fh[q][5]) + bf2f(fl[q][5]));
        p += w1.z * (bf2f(fh[q][6]) + bf2f(fl[q][6]));
        p += w1.w * (bf2f(fh[q][7]) + bf2f(fl[q][7]));
    }
    return p;
}

__device__ __forceinline__ void mfma_batch(floatx4* acc, const bf16x8* fh,
                                           const bf16x8* fl,
                                           const bf16x8 (&bhi)[4][8],
                                           const short* wlo_s, int uc, int lane,
                                           int kt0)
{
    #pragma unroll
    for (int q = 0; q < 4; ++q) {
        const int kt = kt0 + q;
        #pragma unroll
        for (int g = 0; g < 4; ++g) {
            bf16x8 bl = *(const bf16x8*)(wlo_s + ((uc * 4 + g) * 8 + kt) * 512 + lane * 8);
            acc[g] = __builtin_amdgcn_mfma_f32_16x16x32_bf16(fh[q], bhi[g][kt], acc[g], 0, 0, 0);
            acc[g] = __builtin_amdgcn_mfma_f32_16x16x32_bf16(fl[q], bhi[g][kt], acc[g], 0, 0, 0);
            acc[g] = __builtin_amdgcn_mfma_f32_16x16x32_bf16(fh[q], bl,         acc[g], 0, 0, 0);
        }
    }
}

// ---------------------------------------------------------------------------
// Step loop. h is exchanged UNPACKED in [row][k] layout; each wave loads its
// MFMA A-fragments straight from L2 (LOC) or LLC (fallback) — no LDS staging,
// no unpack VALU. Warm steps: 1 syncthreads + LLC barrier. Forecast steps add
// one sync for the y exchange. Step barrier: proven agent-scope LLC path.
// ---------------------------------------------------------------------------
template<bool LOC>
__device__ __forceinline__ void run_steps(
    const short* __restrict__ wlo_s, float* __restrict__ y_s,
    const float* __restrict__ xT, uint* __restrict__ bar,
    short* __restrict__ hb,           // HHI parity-0 base
    const float* __restrict__ fcw, float* __restrict__ out,
    const bf16x8 (&bhi)[4][8], float (&c)[4],
    const float (&bbg)[4], const float (&wig)[4],
    const float fcb0, const int tid, const int rg, const int s,
    const int lane, const int quad, const int uc, const int rt)
{
    const int nof  = lane & 15;
    const int kgrp = lane >> 4;
    const int u    = s * 32 + uc * 16 + nof;
    const size_t lane_off = (size_t)rg * 16384 + (size_t)(rt * 16 + nof) * 256 + kgrp * 8;

    for (int t = 0; t <= SEQ; ++t) {
        const uint par = (uint)t & 1u;
        const short* phi = hb + (size_t)par * HPAR + lane_off;
        const short* plo = phi + HLO_S;

        if (t == SEQ) {          // final y only
            if (uc == 0) {
                bf16x8 fh[4], fl[4];
                float p = 0.f;
                frag_load<LOC>(fh, fl, phi, plo, 0);
                p = yacc(p, fh, fl, fcw, kgrp, 0);
                frag_load<LOC>(fh, fl, phi, plo, 4);
                p = yacc(p, fh, fl, fcw, kgrp, 4);
                p += __shfl_xor(p, 16);
                p += __shfl_xor(p, 32);
                if (lane < 16) y_s[rt * 16 + lane] = p;
            }
            __syncthreads();
            if (s == 0 && tid < 64)
                out[(rg * 64 + tid) * FLEN + (FLEN - 1)] = y_s[tid] + fcb0;
            break;
        }

        const bool fc = (t >= WARM);
        float4 xv;
        if (!fc)
            xv = *(const float4*)(xT + t * 2048 + rg * 64 + rt * 16 + quad * 4);

        // ---- A-fragments straight from cache + MFMA (+ y partials) ----
        floatx4 acc[4];
        #pragma unroll
        for (int g = 0; g < 4; ++g) acc[g] = (floatx4){0.f, 0.f, 0.f, 0.f};
        float p = 0.f;
        {
            bf16x8 fh[4], fl[4];
            frag_load<LOC>(fh, fl, phi, plo, 0);
            if (fc && uc == 0) p = yacc(p, fh, fl, fcw, kgrp, 0);
            mfma_batch(acc, fh, fl, bhi, wlo_s, uc, lane, 0);
            frag_load<LOC>(fh, fl, phi, plo, 4);
            if (fc && uc == 0) p = yacc(p, fh, fl, fcw, kgrp, 4);
            mfma_batch(acc, fh, fl, bhi, wlo_s, uc, lane, 4);
        }

        if (fc) {                // y(t-1) exchange within block
            if (uc == 0) {
                p += __shfl_xor(p, 16);
                p += __shfl_xor(p, 32);
                if (lane < 16) y_s[rt * 16 + lane] = p;
            }
            __syncthreads();
            if (t >= WARM + 1 && s == 0 && tid < 64)
                out[(rg * 64 + tid) * FLEN + (t - (WARM + 1))] = y_s[tid] + fcb0;
        }

        // ---- elementwise LSTM + unpacked h store ([row][k] scatter) ----
        short* dhi = hb + (size_t)(1u - par) * HPAR + (size_t)rg * 16384;
        const float xin[4] = {xv.x, xv.y, xv.z, xv.w};
        #pragma unroll
        for (int i = 0; i < 4; ++i) {
            const int rlow = quad * 4 + i;
            float inr = fc ? (y_s[rt * 16 + rlow] + fcb0) : xin[i];
            float gi = acc[0][i] + bbg[0] + inr * wig[0];
            float gf = acc[1][i] + bbg[1] + inr * wig[1];
            float gg = acc[2][i] + bbg[2] + inr * wig[2];
            float go = acc[3][i] + bbg[3] + inr * wig[3];
            float cn = fast_sig(gf) * c[i] + fast_sig(gi) * fast_tanh(gg);
            c[i] = cn;
            float h = fast_sig(go) * fast_tanh(cn);
            short hi = f2bf(h);
            short lo = f2bf(h - bf2f(hi));
            const int off = (rt * 16 + rlow) * 256 + u;
            if constexpr (LOC) {        // write-through L1 -> shared L2
                dhi[off]         = hi;
                dhi[off + HLO_S] = lo;
            } else {                    // device-coherent store (LLC)
                asm volatile("global_store_short %0, %1, off sc0 sc1"
                             :: "v"(dhi + off), "v"((uint)(unsigned short)hi) : "memory");
                asm volatile("global_store_short %0, %1, off sc0 sc1"
                             :: "v"(dhi + off + HLO_S), "v"((uint)(unsigned short)lo) : "memory");
            }
        }
        asm volatile("s_waitcnt vmcnt(0)" ::: "memory");   // h stores acked
        __syncthreads();                                    // whole block done

        // ---- inter-block step barrier: proven agent-scope LLC path ----
        if (tid == 0) {
            __hip_atomic_fetch_add(&bar[rg * 64], 1u, __ATOMIC_RELAXED,
                                   __HIP_MEMORY_SCOPE_AGENT);
            const uint target = 8u * (uint)(t + 1);
            while (__hip_atomic_load(&bar[rg * 64], __ATOMIC_RELAXED,
                                     __HIP_MEMORY_SCOPE_AGENT) < target)
                __builtin_amdgcn_s_sleep(1);
        }
        __syncthreads();
    }
}

__global__ void __launch_bounds__(512, 2) lstm_main(
    const float* __restrict__ c0, unsigned char* __restrict__ ws,
    const float* __restrict__ fcw, const float* __restrict__ fcb,
    float* __restrict__ out)
{
    extern __shared__ char smem[];
    short* wlo_s = (short*)smem;                  // 32768 shorts (64 KB)
    float* y_s   = (float*)(smem + 65536);        // 64 floats

    const int tid  = threadIdx.x;
    const int blk  = blockIdx.x;
    const int rg   = blk & 31;                    // row-group: 64 rows
    const int s    = blk >> 5;                    // unit-slice: 32 units
    const int wv   = tid >> 6, lane = tid & 63;
    const int quad = lane >> 4, nof = lane & 15;
    const int uc   = wv & 1, rt = wv >> 1;        // wave = (row-tile rt, unit-chunk uc)

    const short* whi_g = (const short*)(ws + WHI_OFF);
    const float* bb    = (const float*)(ws + BB_OFF);
    const float* wi    = (const float*)(ws + WI_OFF);
    const float* xT    = (const float*)(ws + XT_OFF);
    uint* bar          = (uint*)(ws + BAR_OFF);
    short* hb          = (short*)(ws + HG_OFF);

    // ---- stage W-lo slice -> LDS (64 KB contiguous) ----
    {
        const uint4* src = (const uint4*)(ws + WLO_OFF) + (size_t)s * 4096;
        uint4* dst = (uint4*)wlo_s;
        for (int i = tid; i < 4096; i += 512) dst[i] = src[i];
    }
    // ---- W-hi fragments -> registers/AGPRs (32 x 16B per lane) ----
    bf16x8 bhi[4][8];
    {
        const bf16x8* src = (const bf16x8*)whi_g;
        #pragma unroll
        for (int g = 0; g < 4; ++g)
            #pragma unroll
            for (int kt = 0; kt < 8; ++kt)
                bhi[g][kt] = src[(size_t)(((s * 2 + uc) * 4 + g) * 8 + kt) * 64 + lane];
    }

    // ---- per-thread constants ----
    const int u = s * 32 + uc * 16 + nof;         // owned hidden unit (elementwise)
    float bbg[4], wig[4];
    #pragma unroll
    for (int g = 0; g < 4; ++g) { bbg[g] = bb[g * 256 + u]; wig[g] = wi[g * 256 + u]; }
    const float fcb0 = fcb[0];
    float c[4];
    #pragma unroll
    for (int i = 0; i < 4; ++i)
        c[i] = c0[(rg * 64 + rt * 16 + quad * 4 + i) * HDIM + u];

    // ---- XCD co-location check (rg-uniform verdict; fallback = LLC) ----
    if (tid == 0) {
        store_llc32(&bar[rg * 64 + 32 + s], get_xcc_id() + 1u);
        asm volatile("s_waitcnt vmcnt(0)" ::: "memory");
        __hip_atomic_fetch_add(&bar[rg * 64 + 16], 1u, __ATOMIC_RELAXED,
                               __HIP_MEMORY_SCOPE_AGENT);
        while (__hip_atomic_load(&bar[rg * 64 + 16], __ATOMIC_RELAXED,
                                 __HIP_MEMORY_SCOPE_AGENT) < 8u)
            __builtin_amdgcn_s_sleep(1);
        const uint x0 = load_llc32u(&bar[rg * 64 + 32]);
        int ok = 1;
        #pragma unroll
        for (int j = 1; j < 8; ++j)
            ok &= (load_llc32u(&bar[rg * 64 + 32 + j]) == x0);
        ((int*)y_s)[0] = ok;
    }
    __syncthreads();
    const int l2loc = ((int*)y_s)[0];
    __syncthreads();

    if (l2loc)
        run_steps<true>(wlo_s, y_s, xT, bar, hb, fcw, out, bhi, c, bbg, wig,
                        fcb0, tid, rg, s, lane, quad, uc, rt);
    else
        run_steps<false>(wlo_s, y_s, xT, bar, hb, fcw, out, bhi, c, bbg, wig,
                         fcb0, tid, rg, s, lane, quad, uc, rt);
}

extern "C" void kernel_launch(void* const* d_in, const int* in_sizes, int n_in,
                              void* d_out, int out_size, void* d_ws, size_t ws_size,
                              hipStream_t stream) {
    const float* x    = (const float*)d_in[0];
    const float* h0   = (const float*)d_in[1];
    const float* c0   = (const float*)d_in[2];
    const float* W_ih = (const float*)d_in[3];
    const float* W_hh = (const float*)d_in[4];
    const float* b_ih = (const float*)d_in[5];
    const float* b_hh = (const float*)d_in[6];
    const float* fc_w = (const float*)d_in[7];
    const float* fc_b = (const float*)d_in[8];
    float* out = (float*)d_out;
    unsigned char* ws = (unsigned char*)d_ws;

    lstm_prep<<<2048, 256, 0, stream>>>(W_ih, W_hh, b_ih, b_hh, h0, x, ws);

    static int attr_set = 0;
    if (!attr_set) {
        (void)hipFuncSetAttribute((const void*)lstm_main,
                                  hipFuncAttributeMaxDynamicSharedMemorySize, LDS_BYTES);
        attr_set = 1;
    }
    void* args[] = {(void*)&c0, (void*)&ws, (void*)&fc_w, (void*)&fc_b, (void*)&out};
    (void)hipLaunchCooperativeKernel((const void*)lstm_main, dim3(256), dim3(512),
                                     args, LDS_BYTES, stream);
}

// Round 6
// 719.853 us; speedup vs baseline: 1.2361x; 1.2361x over previous
//
#include <hip/hip_runtime.h>

#define SEQ   120
#define WARM  96
#define FLEN  24
#define HDIM  256

typedef __attribute__((ext_vector_type(8))) short bf16x8;
typedef __attribute__((ext_vector_type(4))) float floatx4;
typedef __attribute__((ext_vector_type(4))) unsigned int uintx4;
typedef unsigned int uint;
typedef unsigned long long ull;

// ws layout (bytes):
//   WHI  [0, 512K)        bf16 frag-linear W-hi
//   WLO  [512K, 1M)       bf16 frag-linear W-lo
//   BB   [1M, +4K)        f32 b_ih+b_hh
//   WI   [1M+4K, +4K)     f32 W_ih col
//   BAR  [1M+8K, +8K)     uint bar[32], stride 64 uints (256 B)
//                         +0: step barrier, +16: init barrier, +32..39: xcc ids
//   HG   [1M+16K, +4M)    uint h packed (hi<<16|lo), 2 parities x 32 rg x 16384
//   XT   [5M+16K, +960K)  f32 x transposed [t][row]
#define WHI_OFF 0
#define WLO_OFF (512 * 1024)
#define BB_OFF  (1024 * 1024)
#define WI_OFF  (1024 * 1024 + 4096)
#define BAR_OFF (1024 * 1024 + 8192)
#define HG_OFF  (1024 * 1024 + 16384)
#define HG_PAR  524288              // uints per parity
#define XT_OFF  (HG_OFF + 4 * 1024 * 1024)

#define LDS_BYTES 131328            // wlo 64K | hhi 32K | hlo 32K | y 256B

__device__ __forceinline__ short f2bf(float v) {
    unsigned u = __float_as_uint(v);
    u += 0x7FFF + ((u >> 16) & 1);              // RNE
    return (short)(u >> 16);
}
__device__ __forceinline__ float bf2f(short s) {
    return __uint_as_float(((unsigned)(unsigned short)s) << 16);
}
// v_rcp_f32 (~1 ulp) instead of IEEE divide (div_scale/fmas/fixup ~10 ops):
__device__ __forceinline__ float fast_rcp(float x) {
    return __builtin_amdgcn_rcpf(x);
}
__device__ __forceinline__ float fast_sig(float x) {
    return fast_rcp(1.0f + __expf(-x));
}
__device__ __forceinline__ float fast_tanh(float x) {
    return 1.0f - 2.0f * fast_rcp(__expf(2.0f * x) + 1.0f);
}

// ---- LLC-coherent (cross-XCD) helpers: agent scope -> device SC bits ----
__device__ __forceinline__ ull load_llc64(const ull* p) {
    return __hip_atomic_load(p, __ATOMIC_RELAXED, __HIP_MEMORY_SCOPE_AGENT);
}
__device__ __forceinline__ uint load_llc32u(const uint* p) {
    return __hip_atomic_load(p, __ATOMIC_RELAXED, __HIP_MEMORY_SCOPE_AGENT);
}
__device__ __forceinline__ void store_llc32(uint* p, uint v) {
    __hip_atomic_store(p, v, __ATOMIC_RELAXED, __HIP_MEMORY_SCOPE_AGENT);
}

// XCC (XCD) id of the CU executing this wave [measured: learn_hip m09]
__device__ __forceinline__ uint get_xcc_id() {
    uint x;
    asm volatile("s_getreg_b32 %0, hwreg(HW_REG_XCC_ID)" : "=s"(x));
    return x;
}

__global__ __launch_bounds__(256) void lstm_prep(
    const float* __restrict__ W_ih, const float* __restrict__ W_hh,
    const float* __restrict__ b_ih, const float* __restrict__ b_hh,
    const float* __restrict__ h0, const float* __restrict__ x,
    unsigned char* __restrict__ ws)
{
    int tid = blockIdx.x * 256 + threadIdx.x;       // grid 2048*256 = 524288
    if (tid < 262144) {
        int col = tid >> 8, k = tid & 255;          // col = gate*256+unit
        float v  = W_hh[tid];
        short hi = f2bf(v);
        short lo = f2bf(v - bf2f(hi));
        int g = col >> 8, rem = col & 255;
        int s = rem >> 5, uo = rem & 31, uc = uo >> 4, n = uo & 15;
        int kt = k >> 5, kq = (k >> 3) & 3, j = k & 7;
        size_t unit = ((((size_t)(s * 2 + uc) * 4 + g) * 8 + kt) * 64 + kq * 16 + n);
        ((short*)(ws + WHI_OFF))[unit * 8 + j] = hi;
        ((short*)(ws + WLO_OFF))[unit * 8 + j] = lo;
    }
    if (tid < 524288) {                              // pack h0 -> parity 0
        int row = tid >> 8, k = tid & 255;
        float v  = h0[tid];
        short hi = f2bf(v);
        short lo = f2bf(v - bf2f(hi));
        int rg = row >> 6, rt = (row >> 4) & 3, rlow = row & 15;
        int kt = k >> 5, kq = (k >> 3) & 3, kk = k & 7;
        size_t idx = (size_t)rg * 16384 + (size_t)((((rt * 8 + kt) * 4 + kq) * 16 + rlow) * 8 + kk);
        ((uint*)(ws + HG_OFF))[idx] =
            ((uint)(unsigned short)hi << 16) | (uint)(unsigned short)lo;
    }
    if (tid < 2048 * SEQ) {                          // x transpose -> [t][row]
        int row = tid / SEQ, tt = tid % SEQ;
        ((float*)(ws + XT_OFF))[tt * 2048 + row] = x[tid];
    }
    if (tid < 1024) {
        ((float*)(ws + BB_OFF))[tid] = b_ih[tid] + b_hh[tid];
        ((float*)(ws + WI_OFF))[tid] = W_ih[tid];
    }
    if (tid < 32) {
        ((uint*)(ws + BAR_OFF))[tid * 64]      = 0;   // step barrier
        ((uint*)(ws + BAR_OFF))[tid * 64 + 16] = 0;   // init barrier
    }
}

// ---------------------------------------------------------------------------
// Main step loop, templated on the DATA communication path only.
//   LOC = true : all 8 blocks of this row-group verified on ONE XCD ->
//                h exchange through the shared per-XCD L2:
//                  stores : plain write-through (workgroup-scope atomic store)
//                  loads  : sc0 (bypass possibly-stale L1, served by L2)
//   LOC = false: agent-scope (LLC) path, correct on any block->XCD mapping.
// The inter-block STEP BARRIER is the proven agent-scope LLC barrier in BOTH
// modes. Ordering for LOC: stores write through into the shared L2, vmcnt(0)
// acks them BEFORE the agent-scope add leaves the XCD; a peer observing the
// LLC counter therefore finds the h lines already present in the shared L2.
// ---------------------------------------------------------------------------
template<bool LOC>
__device__ __forceinline__ void run_steps(
    short* __restrict__ wlo_s, short* __restrict__ hhi_s, short* __restrict__ hlo_s,
    float* __restrict__ y_s, const float* __restrict__ xT,
    uint* __restrict__ bar, uint* __restrict__ hg, float* __restrict__ out,
    const bf16x8 (&bhi)[4][8], float (&c)[4],
    const float (&bbg)[4], const float (&wig)[4], const float (&fcw8)[8],
    const float fcb0, const int tid, const int rg, const int s,
    const int lane, const int quad, const int uc, const int rt,
    const int kq_u, const int kk_u)
{
    for (int t = 0; t <= SEQ; ++t) {
        const uint par = (uint)t & 1u;
        const uint* __restrict__ hsrc = hg + (size_t)par * HG_PAR + (size_t)rg * 16384;

        float4 xv;
        if (t < WARM)
            xv = *(const float4*)(xT + t * 2048 + rg * 64 + rt * 16 + quad * 4);

        // ---- staging: h(t-1) -> registers ----
        uintx4 av[8];
        if (LOC) {
            // sc0 (legacy glc): bypass this CU's L1, served by the shared L2.
            const unsigned char* hb = (const unsigned char*)hsrc + 16 * (size_t)tid;
            #pragma unroll
            for (int m = 0; m < 8; ++m)
                asm volatile("global_load_dwordx4 %0, %1, off sc0"
                             : "=v"(av[m]) : "v"(hb + 8192 * m));
            asm volatile("s_waitcnt vmcnt(0)" ::: "memory");
            __builtin_amdgcn_sched_barrier(0);      // rule #18: pin consumers
        } else {
            const ull* hsp64 = (const ull*)hsrc + 2 * tid;
            ull e[16];
            #pragma unroll
            for (int m = 0; m < 8; ++m) {
                e[2 * m]     = load_llc64(hsp64 + 1024 * m);
                e[2 * m + 1] = load_llc64(hsp64 + 1024 * m + 1);
            }
            #pragma unroll
            for (int m = 0; m < 8; ++m) {
                av[m][0] = (uint)e[2 * m];
                av[m][1] = (uint)(e[2 * m] >> 32);
                av[m][2] = (uint)e[2 * m + 1];
                av[m][3] = (uint)(e[2 * m + 1] >> 32);
            }
        }

        // ---- unpack -> LDS frags (v_perm_b32) + y partials (forecast) ----
        // perm semantics: bytes 0-3 of {src0:src1} = src1 (2nd arg), 4-7 = src0.
        // 0x07060302 -> (a[0]>>16) | (a[1] & 0xFFFF0000)   == R2's hi2 expr
        // 0x05040100 -> (a[0] & 0xFFFF) | (a[1] << 16)     == R2's lo2 expr
        #pragma unroll
        for (int m = 0; m < 8; ++m) {
            const uintx4 a = av[m];
            const int base = 4 * tid + 2048 * m;    // short index
            uint2 hi2, lo2;
            hi2.x = __builtin_amdgcn_perm(a[1], a[0], 0x07060302u);
            lo2.x = __builtin_amdgcn_perm(a[1], a[0], 0x05040100u);
            hi2.y = __builtin_amdgcn_perm(a[3], a[2], 0x07060302u);
            lo2.y = __builtin_amdgcn_perm(a[3], a[2], 0x05040100u);
            *(uint2*)(hhi_s + base) = hi2;
            *(uint2*)(hlo_s + base) = lo2;
            if (t >= WARM) {
                const int w9 = tid + 512 * m;
                const int row = ((w9 >> 10) << 4) | ((w9 >> 1) & 15);
                const float* f4 = &fcw8[(m & 1) * 4];
                float p;
                p  = f4[0] * (__uint_as_float(a[0] & 0xFFFF0000u) + __uint_as_float(a[0] << 16));
                p += f4[1] * (__uint_as_float(a[1] & 0xFFFF0000u) + __uint_as_float(a[1] << 16));
                p += f4[2] * (__uint_as_float(a[2] & 0xFFFF0000u) + __uint_as_float(a[2] << 16));
                p += f4[3] * (__uint_as_float(a[3] & 0xFFFF0000u) + __uint_as_float(a[3] << 16));
                atomicAdd(&y_s[row], p);
            }
        }
        __syncthreads();      // h frags + y_s complete

        if (t >= WARM + 1 && s == 0 && tid < 64)
            out[(rg * 64 + tid) * FLEN + (t - (WARM + 1))] = y_s[tid] + fcb0;
        if (t == SEQ) break;

        // ---- MFMA: gates = h @ W^T (3-pass hi/lo), W-hi regs, W-lo LDS ----
        floatx4 acc[4];
        #pragma unroll
        for (int g = 0; g < 4; ++g) acc[g] = (floatx4){0.f, 0.f, 0.f, 0.f};
        #pragma unroll
        for (int kt = 0; kt < 8; ++kt) {
            bf16x8 ah = *(const bf16x8*)(hhi_s + (rt * 8 + kt) * 512 + lane * 8);
            bf16x8 al = *(const bf16x8*)(hlo_s + (rt * 8 + kt) * 512 + lane * 8);
            #pragma unroll
            for (int g = 0; g < 4; ++g) {
                bf16x8 bl = *(const bf16x8*)(wlo_s + ((uc * 4 + g) * 8 + kt) * 512 + lane * 8);
                acc[g] = __builtin_amdgcn_mfma_f32_16x16x32_bf16(ah, bhi[g][kt], acc[g], 0, 0, 0);
                acc[g] = __builtin_amdgcn_mfma_f32_16x16x32_bf16(al, bhi[g][kt], acc[g], 0, 0, 0);
                acc[g] = __builtin_amdgcn_mfma_f32_16x16x32_bf16(ah, bl,         acc[g], 0, 0, 0);
            }
        }

        // ---- elementwise LSTM (thread-local on C-fragments) + h store ----
        uint* __restrict__ hdst = hg + (size_t)(1u - par) * HG_PAR + (size_t)rg * 16384;
        const float xin[4] = {xv.x, xv.y, xv.z, xv.w};
        #pragma unroll
        for (int i = 0; i < 4; ++i) {
            const int rlow = quad * 4 + i;
            float inr = (t < WARM) ? xin[i] : (y_s[rt * 16 + rlow] + fcb0);
            float gi = acc[0][i] + bbg[0] + inr * wig[0];
            float gf = acc[1][i] + bbg[1] + inr * wig[1];
            float gg = acc[2][i] + bbg[2] + inr * wig[2];
            float go = acc[3][i] + bbg[3] + inr * wig[3];
            float cn = fast_sig(gf) * c[i] + fast_sig(gi) * fast_tanh(gg);
            c[i] = cn;
            float h = fast_sig(go) * fast_tanh(cn);
            short hi = f2bf(h);
            short lo = f2bf(h - bf2f(hi));
            const uint hval = ((uint)(unsigned short)hi << 16) | (uint)(unsigned short)lo;
            uint* hp = hdst + ((((rt * 8 + s) * 4 + kq_u) * 16 + rlow) * 8 + kk_u);
            if (LOC)    // write-through L1 -> lands (and stays) in shared L2
                __hip_atomic_store(hp, hval, __ATOMIC_RELAXED, __HIP_MEMORY_SCOPE_WORKGROUP);
            else
                store_llc32(hp, hval);
        }
        asm volatile("s_waitcnt vmcnt(0)" ::: "memory");   // h stores acked (L2 if LOC)
        __syncthreads();                                    // whole block done

        // ---- inter-block step barrier: proven agent-scope LLC path ----
        if (tid < 64) y_s[tid] = 0.f;
        if (tid == 0) {
            __hip_atomic_fetch_add(&bar[rg * 64], 1u, __ATOMIC_RELAXED,
                                   __HIP_MEMORY_SCOPE_AGENT);
            const uint target = 8u * (uint)(t + 1);
            while (__hip_atomic_load(&bar[rg * 64], __ATOMIC_RELAXED,
                                     __HIP_MEMORY_SCOPE_AGENT) < target)
                __builtin_amdgcn_s_sleep(1);
        }
        __syncthreads();
    }
}

__global__ void __launch_bounds__(512, 2) lstm_main(
    const float* __restrict__ c0, unsigned char* __restrict__ ws,
    const float* __restrict__ fcw, const float* __restrict__ fcb,
    float* __restrict__ out)
{
    extern __shared__ char smem[];
    short* wlo_s = (short*)smem;                  // 32768 shorts (64 KB)
    short* hhi_s = (short*)(smem + 65536);        // 16384 shorts
    short* hlo_s = (short*)(smem + 98304);        // 16384 shorts
    float* y_s   = (float*)(smem + 131072);       // 64 floats

    const int tid  = threadIdx.x;
    const int blk  = blockIdx.x;
    const int rg   = blk & 31;                    // row-group: 64 rows
    const int s    = blk >> 5;                    // unit-slice: 32 units
    const int wv   = tid >> 6, lane = tid & 63;
    const int quad = lane >> 4, nof = lane & 15;
    const int uc   = wv & 1, rt = wv >> 1;        // wave = (row-tile rt, unit-chunk uc)

    const short* whi_g = (const short*)(ws + WHI_OFF);
    const float* bb    = (const float*)(ws + BB_OFF);
    const float* wi    = (const float*)(ws + WI_OFF);
    const float* xT    = (const float*)(ws + XT_OFF);
    uint* bar          = (uint*)(ws + BAR_OFF);
    uint* hg           = (uint*)(ws + HG_OFF);

    // ---- stage W-lo slice -> LDS (64 KB contiguous) ----
    {
        const uint4* src = (const uint4*)(ws + WLO_OFF) + (size_t)s * 4096;
        uint4* dst = (uint4*)wlo_s;
        for (int i = tid; i < 4096; i += 512) dst[i] = src[i];
    }
    // ---- W-hi fragments -> registers/AGPRs (32 x 16B per lane) ----
    bf16x8 bhi[4][8];
    {
        const bf16x8* src = (const bf16x8*)whi_g;
        #pragma unroll
        for (int g = 0; g < 4; ++g)
            #pragma unroll
            for (int kt = 0; kt < 8; ++kt)
                bhi[g][kt] = src[(size_t)(((s * 2 + uc) * 4 + g) * 8 + kt) * 64 + lane];
    }

    // ---- per-thread constants ----
    const int u = s * 32 + uc * 16 + nof;         // owned hidden unit (elementwise)
    float bbg[4], wig[4];
    #pragma unroll
    for (int g = 0; g < 4; ++g) { bbg[g] = bb[g * 256 + u]; wig[g] = wi[g * 256 + u]; }
    float fcw8[8];
    #pragma unroll
    for (int mm = 0; mm < 2; ++mm)
        #pragma unroll
        for (int cc = 0; cc < 4; ++cc)
            fcw8[mm * 4 + cc] =
                fcw[((((tid >> 7) + 4 * mm) & 7) << 5) + (((tid >> 5) & 3) << 3) +
                    ((tid & 1) << 2) + cc];
    const float fcb0 = fcb[0];
    float c[4];
    #pragma unroll
    for (int i = 0; i < 4; ++i)
        c[i] = c0[(rg * 64 + rt * 16 + quad * 4 + i) * HDIM + u];
    const int kq_u = uc * 2 + (nof >> 3);
    const int kk_u = nof & 7;

    // ---- XCD co-location check: rg-uniform verdict; fallback = LLC ----
    if (tid < 64) y_s[tid] = 0.f;
    if (tid == 0) {
        store_llc32(&bar[rg * 64 + 32 + s], get_xcc_id() + 1u);
        asm volatile("s_waitcnt vmcnt(0)" ::: "memory");
        __hip_atomic_fetch_add(&bar[rg * 64 + 16], 1u, __ATOMIC_RELAXED,
                               __HIP_MEMORY_SCOPE_AGENT);
        while (__hip_atomic_load(&bar[rg * 64 + 16], __ATOMIC_RELAXED,
                                 __HIP_MEMORY_SCOPE_AGENT) < 8u)
            __builtin_amdgcn_s_sleep(1);
        const uint x0 = load_llc32u(&bar[rg * 64 + 32]);
        int ok = 1;
        #pragma unroll
        for (int j = 1; j < 8; ++j)
            ok &= (load_llc32u(&bar[rg * 64 + 32 + j]) == x0);
        ((int*)hhi_s)[0] = ok;
    }
    __syncthreads();
    const int l2loc = ((int*)hhi_s)[0];
    __syncthreads();    // flag consumed before first staging overwrites hhi_s

    if (l2loc)
        run_steps<true>(wlo_s, hhi_s, hlo_s, y_s, xT, bar, hg, out, bhi, c,
                        bbg, wig, fcw8, fcb0, tid, rg, s, lane, quad, uc, rt,
                        kq_u, kk_u);
    else
        run_steps<false>(wlo_s, hhi_s, hlo_s, y_s, xT, bar, hg, out, bhi, c,
                         bbg, wig, fcw8, fcb0, tid, rg, s, lane, quad, uc, rt,
                         kq_u, kk_u);
}

extern "C" void kernel_launch(void* const* d_in, const int* in_sizes, int n_in,
                              void* d_out, int out_size, void* d_ws, size_t ws_size,
                              hipStream_t stream) {
    const float* x    = (const float*)d_in[0];
    const float* h0   = (const float*)d_in[1];
    const float* c0   = (const float*)d_in[2];
    const float* W_ih = (const float*)d_in[3];
    const float* W_hh = (const float*)d_in[4];
    const float* b_ih = (const float*)d_in[5];
    const float* b_hh = (const float*)d_in[6];
    const float* fc_w = (const float*)d_in[7];
    const float* fc_b = (const float*)d_in[8];
    float* out = (float*)d_out;
    unsigned char* ws = (unsigned char*)d_ws;

    lstm_prep<<<2048, 256, 0, stream>>>(W_ih, W_hh, b_ih, b_hh, h0, x, ws);

    static int attr_set = 0;
    if (!attr_set) {
        (void)hipFuncSetAttribute((const void*)lstm_main,
                                  hipFuncAttributeMaxDynamicSharedMemorySize, LDS_BYTES);
        attr_set = 1;
    }
    void* args[] = {(void*)&c0, (void*)&ws, (void*)&fc_w, (void*)&fc_b, (void*)&out};
    (void)hipLaunchCooperativeKernel((const void*)lstm_main, dim3(256), dim3(512),
                                     args, LDS_BYTES, stream);
}

// Round 7
// 543.240 us; speedup vs baseline: 1.6379x; 1.3251x over previous
//
#include <hip/hip_runtime.h>

#define SEQ   120
#define WARM  96
#define FLEN  24
#define HDIM  256

typedef __attribute__((ext_vector_type(8))) short bf16x8;
typedef __attribute__((ext_vector_type(4))) float floatx4;
typedef __attribute__((ext_vector_type(4))) unsigned int uintx4;
typedef unsigned int uint;
typedef unsigned long long ull;

// ws layout (bytes):
//   WHI  [0, 512K)        bf16 frag-linear W-hi
//   WLO  [512K, 1M)       bf16 frag-linear W-lo
//   BB   [1M, +4K)        f32 b_ih+b_hh
//   WI   [1M+4K, +4K)     f32 W_ih col
//   BAR  [1M+8K, +8K)     uint bar[32], stride 64 uints (256 B)
//                         +0: step barrier, +16: init barrier, +32..39: xcc ids
//   HG   [1M+16K, +4M)    uint h packed (hi<<16|lo), 2 parities x 32 rg x 16384
//                         frag-linear: idx = (((rt*8+kt)*4+kq)*16+rlow)*8+kk
//   XT   [5M+16K, +960K)  f32 x transposed [t][row]
#define WHI_OFF 0
#define WLO_OFF (512 * 1024)
#define BB_OFF  (1024 * 1024)
#define WI_OFF  (1024 * 1024 + 4096)
#define BAR_OFF (1024 * 1024 + 8192)
#define HG_OFF  (1024 * 1024 + 16384)
#define HG_PAR  524288              // uints per parity
#define XT_OFF  (HG_OFF + 4 * 1024 * 1024)

#define LDS_BYTES 66816             // wlo 64K | fcw 1K | y 256B

__device__ __forceinline__ short f2bf(float v) {
    unsigned u = __float_as_uint(v);
    u += 0x7FFF + ((u >> 16) & 1);              // RNE
    return (short)(u >> 16);
}
__device__ __forceinline__ float bf2f(short s) {
    return __uint_as_float(((unsigned)(unsigned short)s) << 16);
}
__device__ __forceinline__ float fast_rcp(float x) {
    return __builtin_amdgcn_rcpf(x);
}
__device__ __forceinline__ float fast_sig(float x) {
    return fast_rcp(1.0f + __expf(-x));
}
__device__ __forceinline__ float fast_tanh(float x) {
    return 1.0f - 2.0f * fast_rcp(__expf(2.0f * x) + 1.0f);
}

// ---- LLC-coherent (cross-XCD) helpers: agent scope -> device SC bits ----
__device__ __forceinline__ uint load_llc32u(const uint* p) {
    return __hip_atomic_load(p, __ATOMIC_RELAXED, __HIP_MEMORY_SCOPE_AGENT);
}
__device__ __forceinline__ void store_llc32(uint* p, uint v) {
    __hip_atomic_store(p, v, __ATOMIC_RELAXED, __HIP_MEMORY_SCOPE_AGENT);
}

// XCC (XCD) id of the CU executing this wave [measured: learn_hip m09]
__device__ __forceinline__ uint get_xcc_id() {
    uint x;
    asm volatile("s_getreg_b32 %0, hwreg(HW_REG_XCC_ID)" : "=s"(x));
    return x;
}

// ---- direct frag-load pipeline primitives ----
// LOC: sc0 (bypass stale L1, served by shared L2).  !LOC: sc0 sc1 (LLC).
template<bool LOC>
__device__ __forceinline__ void frag_issue(uintx4& d0, uintx4& d1, const uint* p) {
    if constexpr (LOC) {
        asm volatile("global_load_dwordx4 %0, %1, off sc0" : "=v"(d0) : "v"(p));
        asm volatile("global_load_dwordx4 %0, %1, off sc0" : "=v"(d1) : "v"(p + 4));
    } else {
        asm volatile("global_load_dwordx4 %0, %1, off sc0 sc1" : "=v"(d0) : "v"(p));
        asm volatile("global_load_dwordx4 %0, %1, off sc0 sc1" : "=v"(d1) : "v"(p + 4));
    }
}
// counted waits, dataflow-tied to the consumed pair ("+v": consumers cannot
// hoist past the wait — rule-18 fix pattern). vmcnt counts in issue order;
// the kt-loop region contains no compiler VMEM, so counts are exact.
__device__ __forceinline__ void frag_wait2(uintx4& d0, uintx4& d1) {
    asm volatile("s_waitcnt vmcnt(2)" : "+v"(d0), "+v"(d1) :: "memory");
}
__device__ __forceinline__ void frag_wait0(uintx4& d0, uintx4& d1) {
    asm volatile("s_waitcnt vmcnt(0)" : "+v"(d0), "+v"(d1) :: "memory");
}

union pack16 { uint u[4]; bf16x8 v; };
union upk4   { uintx4 u; float4 f; };

__global__ __launch_bounds__(256) void lstm_prep(
    const float* __restrict__ W_ih, const float* __restrict__ W_hh,
    const float* __restrict__ b_ih, const float* __restrict__ b_hh,
    const float* __restrict__ h0, const float* __restrict__ x,
    unsigned char* __restrict__ ws)
{
    int tid = blockIdx.x * 256 + threadIdx.x;       // grid 2048*256 = 524288
    if (tid < 262144) {
        int col = tid >> 8, k = tid & 255;          // col = gate*256+unit
        float v  = W_hh[tid];
        short hi = f2bf(v);
        short lo = f2bf(v - bf2f(hi));
        int g = col >> 8, rem = col & 255;
        int s = rem >> 5, uo = rem & 31, uc = uo >> 4, n = uo & 15;
        int kt = k >> 5, kq = (k >> 3) & 3, j = k & 7;
        size_t unit = ((((size_t)(s * 2 + uc) * 4 + g) * 8 + kt) * 64 + kq * 16 + n);
        ((short*)(ws + WHI_OFF))[unit * 8 + j] = hi;
        ((short*)(ws + WLO_OFF))[unit * 8 + j] = lo;
    }
    if (tid < 524288) {                              // pack h0 -> parity 0
        int row = tid >> 8, k = tid & 255;
        float v  = h0[tid];
        short hi = f2bf(v);
        short lo = f2bf(v - bf2f(hi));
        int rg = row >> 6, rt = (row >> 4) & 3, rlow = row & 15;
        int kt = k >> 5, kq = (k >> 3) & 3, kk = k & 7;
        size_t idx = (size_t)rg * 16384 + (size_t)((((rt * 8 + kt) * 4 + kq) * 16 + rlow) * 8 + kk);
        ((uint*)(ws + HG_OFF))[idx] =
            ((uint)(unsigned short)hi << 16) | (uint)(unsigned short)lo;
    }
    if (tid < 2048 * SEQ) {                          // x transpose -> [t][row]
        int row = tid / SEQ, tt = tid % SEQ;
        ((float*)(ws + XT_OFF))[tt * 2048 + row] = x[tid];
    }
    if (tid < 1024) {
        ((float*)(ws + BB_OFF))[tid] = b_ih[tid] + b_hh[tid];
        ((float*)(ws + WI_OFF))[tid] = W_ih[tid];
    }
    if (tid < 32) {
        ((uint*)(ws + BAR_OFF))[tid * 64]      = 0;   // step barrier
        ((uint*)(ws + BAR_OFF))[tid * 64 + 16] = 0;   // init barrier
    }
}

// ---------------------------------------------------------------------------
// Step loop, R7: A-fragments loaded DIRECTLY from cache (HG is frag-linear;
// per-lane address formula verified identical to the R6 LDS-read formula:
// (rt*8+kt)*512 + lane*8 == rt*4096 + kt*512 + quad*128 + nof*8).
// 2-ahead pipelined loads with counted vmcnt; in-register perm unpack; y-dot
// as per-row single-writer (quad-shfl reduce). LDS h-staging, its sync, the
// y atomics and y reset are deleted. Barrier/elementwise/stores: R6 verbatim.
// ---------------------------------------------------------------------------
template<bool LOC>
__device__ __forceinline__ void run_steps(
    const short* __restrict__ wlo_s, const float* __restrict__ fcw_l,
    float* __restrict__ y_s, const float* __restrict__ xT,
    uint* __restrict__ bar, uint* __restrict__ hg, float* __restrict__ out,
    const bf16x8 (&bhi)[4][8], float (&c)[4],
    const float (&bbg)[4], const float (&wig)[4],
    const float fcb0, const int tid, const int rg, const int s,
    const int lane, const int quad, const int uc, const int rt,
    const int kq_u, const int kk_u)
{
    const int nof = lane & 15;

    for (int t = 0; t <= SEQ; ++t) {
        const uint par = (uint)t & 1u;
        const uint* __restrict__ hsrc = hg + (size_t)par * HG_PAR + (size_t)rg * 16384;
        const uint* fb = hsrc + rt * 4096 + quad * 128 + nof * 8;

        if (t == SEQ) {          // final y only
            if (uc == 0) {
                float p = 0.f;
                #pragma unroll
                for (int kt = 0; kt < 8; ++kt) {
                    uintx4 a0, a1;
                    frag_issue<LOC>(a0, a1, fb + kt * 512);
                    frag_wait0(a0, a1);
                    pack16 ph, pl;
                    ph.u[0] = __builtin_amdgcn_perm(a0[1], a0[0], 0x07060302u);
                    ph.u[1] = __builtin_amdgcn_perm(a0[3], a0[2], 0x07060302u);
                    ph.u[2] = __builtin_amdgcn_perm(a1[1], a1[0], 0x07060302u);
                    ph.u[3] = __builtin_amdgcn_perm(a1[3], a1[2], 0x07060302u);
                    pl.u[0] = __builtin_amdgcn_perm(a0[1], a0[0], 0x05040100u);
                    pl.u[1] = __builtin_amdgcn_perm(a0[3], a0[2], 0x05040100u);
                    pl.u[2] = __builtin_amdgcn_perm(a1[1], a1[0], 0x05040100u);
                    pl.u[3] = __builtin_amdgcn_perm(a1[3], a1[2], 0x05040100u);
                    const float* w = fcw_l + kt * 32 + quad * 8;
                    const float4 w0 = *(const float4*)(w);
                    const float4 w1 = *(const float4*)(w + 4);
                    p += w0.x * (bf2f(ph.v[0]) + bf2f(pl.v[0]));
                    p += w0.y * (bf2f(ph.v[1]) + bf2f(pl.v[1]));
                    p += w0.z * (bf2f(ph.v[2]) + bf2f(pl.v[2]));
                    p += w0.w * (bf2f(ph.v[3]) + bf2f(pl.v[3]));
                    p += w1.x * (bf2f(ph.v[4]) + bf2f(pl.v[4]));
                    p += w1.y * (bf2f(ph.v[5]) + bf2f(pl.v[5]));
                    p += w1.z * (bf2f(ph.v[6]) + bf2f(pl.v[6]));
                    p += w1.w * (bf2f(ph.v[7]) + bf2f(pl.v[7]));
                }
                p += __shfl_xor(p, 16);
                p += __shfl_xor(p, 32);
                if (lane < 16) y_s[rt * 16 + lane] = p;
            }
            __syncthreads();
            if (s == 0 && tid < 64)
                out[(rg * 64 + tid) * FLEN + (FLEN - 1)] = y_s[tid] + fcb0;
            break;
        }

        const bool fc = (t >= WARM);
        uintx4 xvv;
        if (!fc)         // x(t): own asm load so vmcnt counting stays exact
            asm volatile("global_load_dwordx4 %0, %1, off"
                         : "=v"(xvv)
                         : "v"(xT + t * 2048 + rg * 64 + rt * 16 + quad * 4));

        // ---- pipelined frag loads + in-register unpack + MFMA + y-dot ----
        floatx4 acc[4];
        #pragma unroll
        for (int g = 0; g < 4; ++g) acc[g] = (floatx4){0.f, 0.f, 0.f, 0.f};
        float p = 0.f;
        uintx4 A[3][2];
        frag_issue<LOC>(A[0][0], A[0][1], fb + 0 * 512);
        frag_issue<LOC>(A[1][0], A[1][1], fb + 1 * 512);
        #pragma unroll
        for (int kt = 0; kt < 8; ++kt) {
            const int sl = kt % 3;
            uintx4& a0 = A[sl][0];
            uintx4& a1 = A[sl][1];
            if (kt < 7) frag_wait2(a0, a1); else frag_wait0(a0, a1);
            pack16 ph, pl;
            ph.u[0] = __builtin_amdgcn_perm(a0[1], a0[0], 0x07060302u);
            ph.u[1] = __builtin_amdgcn_perm(a0[3], a0[2], 0x07060302u);
            ph.u[2] = __builtin_amdgcn_perm(a1[1], a1[0], 0x07060302u);
            ph.u[3] = __builtin_amdgcn_perm(a1[3], a1[2], 0x07060302u);
            pl.u[0] = __builtin_amdgcn_perm(a0[1], a0[0], 0x05040100u);
            pl.u[1] = __builtin_amdgcn_perm(a0[3], a0[2], 0x05040100u);
            pl.u[2] = __builtin_amdgcn_perm(a1[1], a1[0], 0x05040100u);
            pl.u[3] = __builtin_amdgcn_perm(a1[3], a1[2], 0x05040100u);
            if (fc && uc == 0) {
                const float* w = fcw_l + kt * 32 + quad * 8;
                const float4 w0 = *(const float4*)(w);
                const float4 w1 = *(const float4*)(w + 4);
                p += w0.x * (bf2f(ph.v[0]) + bf2f(pl.v[0]));
                p += w0.y * (bf2f(ph.v[1]) + bf2f(pl.v[1]));
                p += w0.z * (bf2f(ph.v[2]) + bf2f(pl.v[2]));
                p += w0.w * (bf2f(ph.v[3]) + bf2f(pl.v[3]));
                p += w1.x * (bf2f(ph.v[4]) + bf2f(pl.v[4]));
                p += w1.y * (bf2f(ph.v[5]) + bf2f(pl.v[5]));
                p += w1.z * (bf2f(ph.v[6]) + bf2f(pl.v[6]));
                p += w1.w * (bf2f(ph.v[7]) + bf2f(pl.v[7]));
            }
            #pragma unroll
            for (int g = 0; g < 4; ++g) {
                bf16x8 bl = *(const bf16x8*)(wlo_s + ((uc * 4 + g) * 8 + kt) * 512 + lane * 8);
                acc[g] = __builtin_amdgcn_mfma_f32_16x16x32_bf16(ph.v, bhi[g][kt], acc[g], 0, 0, 0);
                acc[g] = __builtin_amdgcn_mfma_f32_16x16x32_bf16(pl.v, bhi[g][kt], acc[g], 0, 0, 0);
                acc[g] = __builtin_amdgcn_mfma_f32_16x16x32_bf16(ph.v, bl,        acc[g], 0, 0, 0);
            }
            if (kt < 6)
                frag_issue<LOC>(A[(kt + 2) % 3][0], A[(kt + 2) % 3][1],
                                fb + (kt + 2) * 512);
        }

        if (fc) {               // y(t-1) exchange within block (single-writer)
            if (uc == 0) {
                p += __shfl_xor(p, 16);
                p += __shfl_xor(p, 32);
                if (lane < 16) y_s[rt * 16 + lane] = p;
            }
            __syncthreads();
            if (t >= WARM + 1 && s == 0 && tid < 64)
                out[(rg * 64 + tid) * FLEN + (t - (WARM + 1))] = y_s[tid] + fcb0;
        } else {
            // tie xvv into drained state (vmcnt already 0 after kt7's wait)
            asm volatile("s_waitcnt vmcnt(0)" : "+v"(xvv) :: "memory");
        }

        // ---- elementwise LSTM (verbatim R6) + h store ----
        uint* __restrict__ hdst = hg + (size_t)(1u - par) * HG_PAR + (size_t)rg * 16384;
        upk4 xcv; xcv.u = xvv;
        const float xin[4] = {xcv.f.x, xcv.f.y, xcv.f.z, xcv.f.w};
        #pragma unroll
        for (int i = 0; i < 4; ++i) {
            const int rlow = quad * 4 + i;
            float inr = fc ? (y_s[rt * 16 + rlow] + fcb0) : xin[i];
            float gi = acc[0][i] + bbg[0] + inr * wig[0];
            float gf = acc[1][i] + bbg[1] + inr * wig[1];
            float gg = acc[2][i] + bbg[2] + inr * wig[2];
            float go = acc[3][i] + bbg[3] + inr * wig[3];
            float cn = fast_sig(gf) * c[i] + fast_sig(gi) * fast_tanh(gg);
            c[i] = cn;
            float h = fast_sig(go) * fast_tanh(cn);
            short hi = f2bf(h);
            short lo = f2bf(h - bf2f(hi));
            const uint hval = ((uint)(unsigned short)hi << 16) | (uint)(unsigned short)lo;
            uint* hp = hdst + ((((rt * 8 + s) * 4 + kq_u) * 16 + rlow) * 8 + kk_u);
            if (LOC)    // write-through L1 -> lands (and stays) in shared L2
                __hip_atomic_store(hp, hval, __ATOMIC_RELAXED, __HIP_MEMORY_SCOPE_WORKGROUP);
            else
                store_llc32(hp, hval);
        }
        asm volatile("s_waitcnt vmcnt(0)" ::: "memory");   // h stores acked
        __syncthreads();                                    // whole block done

        // ---- inter-block step barrier: proven agent-scope LLC path ----
        if (tid == 0) {
            __hip_atomic_fetch_add(&bar[rg * 64], 1u, __ATOMIC_RELAXED,
                                   __HIP_MEMORY_SCOPE_AGENT);
            const uint target = 8u * (uint)(t + 1);
            while (__hip_atomic_load(&bar[rg * 64], __ATOMIC_RELAXED,
                                     __HIP_MEMORY_SCOPE_AGENT) < target)
                __builtin_amdgcn_s_sleep(1);
        }
        __syncthreads();
    }
}

__global__ void __launch_bounds__(512, 2) lstm_main(
    const float* __restrict__ c0, unsigned char* __restrict__ ws,
    const float* __restrict__ fcw, const float* __restrict__ fcb,
    float* __restrict__ out)
{
    extern __shared__ char smem[];
    short* wlo_s = (short*)smem;                  // 32768 shorts (64 KB)
    float* fcw_l = (float*)(smem + 65536);        // 256 floats (1 KB)
    float* y_s   = (float*)(smem + 66560);        // 64 floats

    const int tid  = threadIdx.x;
    const int blk  = blockIdx.x;
    const int rg   = blk & 31;                    // row-group: 64 rows
    const int s    = blk >> 5;                    // unit-slice: 32 units
    const int wv   = tid >> 6, lane = tid & 63;
    const int quad = lane >> 4, nof = lane & 15;
    const int uc   = wv & 1, rt = wv >> 1;        // wave = (row-tile rt, unit-chunk uc)

    const short* whi_g = (const short*)(ws + WHI_OFF);
    const float* bb    = (const float*)(ws + BB_OFF);
    const float* wi    = (const float*)(ws + WI_OFF);
    const float* xT    = (const float*)(ws + XT_OFF);
    uint* bar          = (uint*)(ws + BAR_OFF);
    uint* hg           = (uint*)(ws + HG_OFF);

    // ---- stage W-lo slice -> LDS (64 KB contiguous) + fcw -> LDS ----
    {
        const uint4* src = (const uint4*)(ws + WLO_OFF) + (size_t)s * 4096;
        uint4* dst = (uint4*)wlo_s;
        for (int i = tid; i < 4096; i += 512) dst[i] = src[i];
        if (tid < 256) fcw_l[tid] = fcw[tid];
    }
    // ---- W-hi fragments -> registers/AGPRs (32 x 16B per lane) ----
    bf16x8 bhi[4][8];
    {
        const bf16x8* src = (const bf16x8*)whi_g;
        #pragma unroll
        for (int g = 0; g < 4; ++g)
            #pragma unroll
            for (int kt = 0; kt < 8; ++kt)
                bhi[g][kt] = src[(size_t)(((s * 2 + uc) * 4 + g) * 8 + kt) * 64 + lane];
    }

    // ---- per-thread constants ----
    const int u = s * 32 + uc * 16 + nof;         // owned hidden unit (elementwise)
    float bbg[4], wig[4];
    #pragma unroll
    for (int g = 0; g < 4; ++g) { bbg[g] = bb[g * 256 + u]; wig[g] = wi[g * 256 + u]; }
    const float fcb0 = fcb[0];
    float c[4];
    #pragma unroll
    for (int i = 0; i < 4; ++i)
        c[i] = c0[(rg * 64 + rt * 16 + quad * 4 + i) * HDIM + u];
    const int kq_u = uc * 2 + (nof >> 3);
    const int kk_u = nof & 7;

    // ---- XCD co-location check: rg-uniform verdict; fallback = LLC ----
    if (tid == 0) {
        store_llc32(&bar[rg * 64 + 32 + s], get_xcc_id() + 1u);
        asm volatile("s_waitcnt vmcnt(0)" ::: "memory");
        __hip_atomic_fetch_add(&bar[rg * 64 + 16], 1u, __ATOMIC_RELAXED,
                               __HIP_MEMORY_SCOPE_AGENT);
        while (__hip_atomic_load(&bar[rg * 64 + 16], __ATOMIC_RELAXED,
                                 __HIP_MEMORY_SCOPE_AGENT) < 8u)
            __builtin_amdgcn_s_sleep(1);
        const uint x0 = load_llc32u(&bar[rg * 64 + 32]);
        int ok = 1;
        #pragma unroll
        for (int j = 1; j < 8; ++j)
            ok &= (load_llc32u(&bar[rg * 64 + 32 + j]) == x0);
        ((int*)y_s)[0] = ok;
    }
    __syncthreads();
    const int l2loc = ((int*)y_s)[0];
    __syncthreads();    // verdict consumed before y_s is reused

    if (l2loc)
        run_steps<true>(wlo_s, fcw_l, y_s, xT, bar, hg, out, bhi, c,
                        bbg, wig, fcb0, tid, rg, s, lane, quad, uc, rt,
                        kq_u, kk_u);
    else
        run_steps<false>(wlo_s, fcw_l, y_s, xT, bar, hg, out, bhi, c,
                         bbg, wig, fcb0, tid, rg, s, lane, quad, uc, rt,
                         kq_u, kk_u);
}

extern "C" void kernel_launch(void* const* d_in, const int* in_sizes, int n_in,
                              void* d_out, int out_size, void* d_ws, size_t ws_size,
                              hipStream_t stream) {
    const float* x    = (const float*)d_in[0];
    const float* h0   = (const float*)d_in[1];
    const float* c0   = (const float*)d_in[2];
    const float* W_ih = (const float*)d_in[3];
    const float* W_hh = (const float*)d_in[4];
    const float* b_ih = (const float*)d_in[5];
    const float* b_hh = (const float*)d_in[6];
    const float* fc_w = (const float*)d_in[7];
    const float* fc_b = (const float*)d_in[8];
    float* out = (float*)d_out;
    unsigned char* ws = (unsigned char*)d_ws;

    lstm_prep<<<2048, 256, 0, stream>>>(W_ih, W_hh, b_ih, b_hh, h0, x, ws);

    static int attr_set = 0;
    if (!attr_set) {
        (void)hipFuncSetAttribute((const void*)lstm_main,
                                  hipFuncAttributeMaxDynamicSharedMemorySize, LDS_BYTES);
        attr_set = 1;
    }
    void* args[] = {(void*)&c0, (void*)&ws, (void*)&fc_w, (void*)&fc_b, (void*)&out};
    (void)hipLaunchCooperativeKernel((const void*)lstm_main, dim3(256), dim3(512),
                                     args, LDS_BYTES, stream);
}